// Round 10
// baseline (237.584 us; speedup 1.0000x reference)
//
#include <hip/hip_runtime.h>

typedef __bf16 bf16;
typedef float f32x4 __attribute__((ext_vector_type(4)));
typedef bf16 bf16x8v __attribute__((ext_vector_type(8)));
typedef bf16 bf16x4v __attribute__((ext_vector_type(4)));

#define MFMA_BF16(a, b, c) __builtin_amdgcn_mfma_f32_16x16x32_bf16((a), (b), (c), 0, 0, 0)

// async global->LDS, 16B per lane (dest = wave-uniform base + lane*16)
__device__ __forceinline__ void async16(const bf16* g, bf16* l) {
  __builtin_amdgcn_global_load_lds(
      (const __attribute__((address_space(1))) void*)g,
      (__attribute__((address_space(3))) void*)l, 16, 0, 0);
}

// ---------------------------------------------------------------------------
// Fused prep: f32->bf16 convert of x  +  two transpose+convert of weights.
// Blocks 0..3071: convert (8 elems/thread).  3072..4799: w_attn transpose.
// 4800..5375: w_proj transpose.
// ---------------------------------------------------------------------------
__global__ __launch_bounds__(256) void prep_kernel(
    const float* __restrict__ x, bf16* __restrict__ xb,
    const float* __restrict__ w_attn, bf16* __restrict__ wt_attn,
    const float* __restrict__ w_proj, bf16* __restrict__ wt_proj) {
  __shared__ float tile[32][33];
  const int b = blockIdx.x;
  if (b < 3072) {
    int i = b * 256 + threadIdx.x;
    const float4* p = (const float4*)x + (size_t)i * 2;
    float4 a = p[0], c = p[1];
    bf16x8v o;
    o[0] = (bf16)a.x; o[1] = (bf16)a.y; o[2] = (bf16)a.z; o[3] = (bf16)a.w;
    o[4] = (bf16)c.x; o[5] = (bf16)c.y; o[6] = (bf16)c.z; o[7] = (bf16)c.w;
    ((bf16x8v*)xb)[i] = o;
    return;
  }
  const float* in;
  bf16* out;
  int Ccols, bidx;
  if (b < 4800) {
    in = w_attn; out = wt_attn; Ccols = 2304; bidx = b - 3072;
  } else {
    in = w_proj; out = wt_proj; Ccols = 768; bidx = b - 4800;
  }
  const int R = 768;
  const int gx = Ccols / 32;
  const int c0 = (bidx % gx) * 32, r0 = (bidx / gx) * 32;
  const int tx = threadIdx.x & 31;
  const int ty = threadIdx.x >> 5;
#pragma unroll
  for (int i = 0; i < 4; ++i) {
    int r = ty + i * 8;
    tile[r][tx] = in[(size_t)(r0 + r) * Ccols + c0 + tx];
  }
  __syncthreads();
#pragma unroll
  for (int i = 0; i < 4; ++i) {
    int c = ty + i * 8;
    out[(size_t)(c0 + c) * R + r0 + tx] = (bf16)tile[tx][c];
  }
}

// ---------------------------------------------------------------------------
// Tiled bf16 transpose: out[z][c][r] = in[z][r][c].  R,C mult of 32.
// ---------------------------------------------------------------------------
__global__ __launch_bounds__(256) void transpose_bf16_kernel(
    const bf16* __restrict__ in, bf16* __restrict__ out, int R, int Ccols) {
  __shared__ bf16 tile[32][33];
  const bf16* inp = in + (size_t)blockIdx.z * R * Ccols;
  bf16* outp = out + (size_t)blockIdx.z * R * Ccols;
  int c0 = blockIdx.x * 32, r0 = blockIdx.y * 32;
  int tx = threadIdx.x & 31;
  int ty = threadIdx.x >> 5;
#pragma unroll
  for (int i = 0; i < 4; ++i) {
    int r = ty + i * 8;
    tile[r][tx] = inp[(size_t)(r0 + r) * Ccols + c0 + tx];
  }
  __syncthreads();
#pragma unroll
  for (int i = 0; i < 4; ++i) {
    int c = ty + i * 8;
    outp[(size_t)(c0 + c) * R + r0 + tx] = tile[tx][c];
  }
}

// ---------------------------------------------------------------------------
// GEMM: out[M][N] = A[M][768] * Bt[N][768]^T + bias[N]   (A,Bt bf16; bias f32)
// MODE 0: store FLOAT to outf.  MODE 1: scatter bf16 into q/k/v [b,h,t,d].
// 128x128 tile, BK=64, 4 waves, async global_load_lds staging with the
// attn-proven XOR swizzle (conflict-free b128 fragment reads).
//
// XCD-AFFINE GRID (T1): 1-D grid; hw round-robin gives xcd = id%8.  Mapping
//   m_tile = xcd*8 + (id/8)%8,  n_tile = id/64
// puts 8 contiguous m-tiles (A-panels, 1.5 MB) + full B (<=3.5 MB) in ONE
// XCD's 4MB L2.  The old dim3(gx,64) order scattered each A-panel's 18
// readers over all 8 XCDs -> ~8x A re-fetch from HBM (R3 showed this class
// of effect is worth 5x traffic on this chip).  Requires GY%8==0, grid%64==0.
// ---------------------------------------------------------------------------
template <int MODE, int GX>
__global__ __launch_bounds__(256) void gemm_kernel(
    const bf16* __restrict__ A, const bf16* __restrict__ Bt,
    const float* __restrict__ bias, int N, float* __restrict__ outf,
    bf16* __restrict__ qo, bf16* __restrict__ ko, bf16* __restrict__ vo) {
  constexpr int Kdim = 768;
  __shared__ __align__(16) bf16 As[128][64];
  __shared__ __align__(16) bf16 Bs[128][64];
  const int tid = threadIdx.x;
  const int lane = tid & 63;
  const int wave = tid >> 6;
  const int wm = (wave >> 1) * 64, wn = (wave & 1) * 64;
  const int id = blockIdx.x;
  const int xcd = id & 7, j = id >> 3;
  const int m0 = (xcd * 8 + (j & 7)) * 128;  // 8 m-tiles per XCD
  const int n0 = (j >> 3) * 128;             // n advances slowest
  const int l15 = lane & 15, q4 = lane >> 4;
  const int swz = l15 & 7;

  f32x4 acc[4][4] = {};

  const int gr = lane >> 3;        // row within 8-row group
  const int sj = (lane & 7) ^ gr;  // global source chunk (XOR swizzle)

  for (int k0 = 0; k0 < Kdim; k0 += 64) {
#pragma unroll
    for (int c = 0; c < 4; ++c) {
      const int r0 = wave * 32 + c * 8;  // 8-row group staged per call
      async16(A + (size_t)(m0 + r0 + gr) * Kdim + k0 + sj * 8, &As[r0][0]);
      async16(Bt + (size_t)(n0 + r0 + gr) * Kdim + k0 + sj * 8, &Bs[r0][0]);
    }
    __syncthreads();
#pragma unroll
    for (int ks = 0; ks < 2; ++ks) {
      bf16x8v af[4], bfg[4];
#pragma unroll
      for (int i = 0; i < 4; ++i)
        af[i] =
            *(const bf16x8v*)&As[wm + i * 16 + l15][((ks * 4 + q4) ^ swz) * 8];
#pragma unroll
      for (int i = 0; i < 4; ++i)
        bfg[i] =
            *(const bf16x8v*)&Bs[wn + i * 16 + l15][((ks * 4 + q4) ^ swz) * 8];
#pragma unroll
      for (int mi = 0; mi < 4; ++mi)
#pragma unroll
        for (int ni = 0; ni < 4; ++ni)
          acc[mi][ni] = MFMA_BF16(af[mi], bfg[ni], acc[mi][ni]);
    }
    __syncthreads();
  }

#pragma unroll
  for (int mi = 0; mi < 4; ++mi) {
#pragma unroll
    for (int ni = 0; ni < 4; ++ni) {
      int col = n0 + wn + ni * 16 + l15;
      float bv = bias[col];
#pragma unroll
      for (int r = 0; r < 4; ++r) {
        int row = m0 + wm + mi * 16 + q4 * 4 + r;
        float val = acc[mi][ni][r] + bv;
        if (MODE == 0) {
          outf[(size_t)row * N + col] = val;
        } else {
          int sel = col / 768;
          int cc = col - sel * 768;
          int h = cc >> 6, d = cc & 63;
          int b = row >> 12, t = row & 4095;
          bf16* dst = sel == 0 ? qo : (sel == 1 ? ko : vo);
          dst[((size_t)(b * 12 + h) * 4096 + t) * 64 + d] = (bf16)val;
        }
      }
    }
  }
}

// ---------------------------------------------------------------------------
// Flash attention — R6 kernel VERBATIM (best measured: 85.6 us; at its
// balanced-wave LDS-pipe structural floor).
// Mirror-pair block {63-p, p}; 8 waves, one 16-row strip per wave.
// p MAP: bh=id%24, p=id/24 (24 = 0 mod 8 -> per-bh XCD/L2 affinity; proven).
// QK^T swapped (mfma(K,Q)); P via 4 ds_write_b64; swizzled b128 PV A-frag.
// 48 KB LDS, 3 blocks/CU, launch_bounds(512,6) = 24 waves/CU.
// ---------------------------------------------------------------------------
__global__ __launch_bounds__(512, 6) void attn_kernel(
    const bf16* __restrict__ q, const bf16* __restrict__ k,
    const bf16* __restrict__ vt, bf16* __restrict__ y) {
  __shared__ __align__(16) bf16 Kb[2][64][64];  // [key][d], swizzled
  __shared__ __align__(16) bf16 Vb[2][64][64];  // [d][key], swizzled
  __shared__ __align__(16) bf16 Ps[8][16][64];  // per-wave P, swizzled
  const int tid = threadIdx.x;
  const int lane = tid & 63, wave = tid >> 6;  // wave 0..7
  const int l15 = lane & 15, q4 = lane >> 4;
  const int swz = l15 & 7;
  const int id = blockIdx.x;
  const int bh = id % 24;
  const int p = id / 24;  // 0..31
  // wave role: one 16-row strip.  waves 0-3: big tile 63-p; 4-7: small tile p
  const int rs = (wave < 4) ? ((63 - p) * 64 + wave * 16)
                            : (p * 64 + (wave - 4) * 16);
  const int hb = bh % 12, bb = bh / 12;

  // staging geometry: one async16 wave-call covers 8 rows x 8 chunks (1 KB);
  // each of 8 waves stages one 8-row group of K and of V.
  const int gr = lane >> 3;        // row within 8-row group
  const int sj = (lane & 7) ^ gr;  // global source chunk (XOR swizzle)
  const bf16* kgbase = k + (size_t)bh * 4096 * 64;
  const bf16* vgbase = vt + (size_t)bh * 64 * 4096;

  bf16x8v ones;
#pragma unroll
  for (int j = 0; j < 8; ++j) ones[j] = (bf16)1.0f;

  // Q fragments for this wave's strip, pre-scaled by log2(e)/sqrt(64)
  bf16x8v qf[2];
  {
    const bf16* qrow = q + ((size_t)bh * 4096 + rs + l15) * 64 + q4 * 8;
#pragma unroll
    for (int ks = 0; ks < 2; ++ks) {
      bf16x8v t8 = *(const bf16x8v*)(qrow + ks * 32);
#pragma unroll
      for (int j = 0; j < 8; ++j) t8[j] = (bf16)((float)t8[j] * 0.18033688f);
      qf[ks] = t8;
    }
  }

  f32x4 o[4] = {};
  f32x4 ol = {};

  auto stage = [&](int kt, int buf) {
    const int t0k = kt * 64;
    async16(kgbase + (size_t)(t0k + wave * 8 + gr) * 64 + sj * 8,
            &Kb[buf][wave * 8][0]);
    async16(vgbase + (size_t)(wave * 8 + gr) * 4096 + t0k + sj * 8,
            &Vb[buf][wave * 8][0]);
  };

  // p = exp2(s - 28.854); full (no mask) variant
  auto sm_full = [&](f32x4 (&s)[4]) {
#pragma unroll
    for (int ni = 0; ni < 4; ++ni)
#pragma unroll
      for (int r = 0; r < 4; ++r)
        s[ni][r] = __builtin_amdgcn_exp2f(s[ni][r] - 28.8539008f);
  };
  // masked variant: local key (ni*16+q4*4+r) valid iff <= lim
  auto sm_mask = [&](f32x4 (&s)[4], int lim) {
#pragma unroll
    for (int ni = 0; ni < 4; ++ni)
#pragma unroll
      for (int r = 0; r < 4; ++r)
        s[ni][r] = (ni * 16 + q4 * 4 + r <= lim)
                       ? __builtin_amdgcn_exp2f(s[ni][r] - 28.8539008f)
                       : 0.0f;
  };
  // P row write: lane (q4,l15) owns keys ni*16 + q4*4 + {0..3} of q-row l15.
  auto pwrite = [&](const f32x4 (&s)[4]) {
#pragma unroll
    for (int ni = 0; ni < 4; ++ni) {
      bf16x4v pv4;
#pragma unroll
      for (int e = 0; e < 4; ++e) pv4[e] = (bf16)s[ni][e];
      const int jb = ni * 2 + (q4 >> 1);
      *(bf16x4v*)&Ps[wave][l15][((jb ^ (l15 & 7)) * 8) + (q4 & 1) * 4] = pv4;
    }
  };

  const int ktmax = 64 - p;  // tiles needed by the big tile
  stage(0, 0);

  for (int kt = 0; kt < ktmax; ++kt) {
    const int buf = kt & 1;
    __syncthreads();  // drains vmcnt: tile kt resident; buf^1 free
    if (kt + 1 < ktmax) stage(kt + 1, buf ^ 1);
    const int t0 = kt * 64;

    if (t0 <= rs + 15) {  // wave-uniform: this strip still has work
      // S^T = K Q^T (exp2 domain)
      // Lane (q4,l15): s[ni][r] = S[qrow = rs + l15][key = t0+ni*16+q4*4+r]
      f32x4 s[4] = {};
      __builtin_amdgcn_s_setprio(1);
#pragma unroll
      for (int ni = 0; ni < 4; ++ni) {
#pragma unroll
        for (int ks = 0; ks < 2; ++ks) {
          bf16x8v kf = *(const bf16x8v*)&Kb[buf][ni * 16 + l15]
                                           [((ks * 4 + q4) ^ swz) * 8];
          s[ni] = MFMA_BF16(kf, qf[ks], s[ni]);
        }
      }
      __builtin_amdgcn_s_setprio(0);

      // softmax + P write (masked only near the diagonal)
      if (t0 + 63 <= rs) sm_full(s); else sm_mask(s, rs + l15 - t0);
      pwrite(s);

      // PV A-frag: proven swizzled b128 read path (row = q_row = l15)
      bf16x8v pf[2];
#pragma unroll
      for (int ks = 0; ks < 2; ++ks)
        pf[ks] = *(const bf16x8v*)&Ps[wave][l15][((ks * 4 + q4) ^ swz) * 8];

      // O += P V ; rowsum l += P * ones
      __builtin_amdgcn_s_setprio(1);
#pragma unroll
      for (int d4 = 0; d4 < 4; ++d4) {
#pragma unroll
        for (int ks = 0; ks < 2; ++ks) {
          bf16x8v vf = *(const bf16x8v*)&Vb[buf][d4 * 16 + l15]
                                           [((ks * 4 + q4) ^ swz) * 8];
          o[d4] = MFMA_BF16(pf[ks], vf, o[d4]);
        }
      }
#pragma unroll
      for (int ks = 0; ks < 2; ++ks) ol = MFMA_BF16(pf[ks], ones, ol);
      __builtin_amdgcn_s_setprio(0);
    }
  }

  // epilogue: y[b][t][h*64+d] = O / l  (fixed-max scale cancels)
  // PV output D-layout: q_row = rs + q4*4 + r, d = d4*16 + l15.
#pragma unroll
  for (int d4 = 0; d4 < 4; ++d4)
#pragma unroll
    for (int r = 0; r < 4; ++r) {
      int row = rs + q4 * 4 + r;
      y[((size_t)(bb * 4096 + row)) * 768 + hb * 64 + d4 * 16 + l15] =
          (bf16)(o[d4][r] / ol[r]);
    }
}

// ---------------------------------------------------------------------------
extern "C" void kernel_launch(void* const* d_in, const int* in_sizes, int n_in,
                              void* d_out, int out_size, void* d_ws,
                              size_t ws_size, hipStream_t stream) {
  const float* x = (const float*)d_in[0];       // (2,4096,768) f32
  const float* w_attn = (const float*)d_in[1];  // (768,2304) f32
  const float* b_attn = (const float*)d_in[2];  // (2304) f32
  const float* w_proj = (const float*)d_in[3];  // (768,768) f32
  const float* b_proj = (const float*)d_in[4];  // (768) f32
  float* out = (float*)d_out;                   // (8192*768) f32

  char* ws = (char*)d_ws;
  size_t off = 0;
  auto carve = [&](size_t elems) {
    char* p = ws + off;
    off += ((elems * sizeof(bf16) + 255) & ~(size_t)255);
    return (bf16*)p;
  };
  bf16* xb = carve((size_t)8192 * 768);      // x bf16; reused as vtb
  bf16* wt_attn = carve((size_t)2304 * 768);
  bf16* wt_proj = carve((size_t)768 * 768);
  bf16* qb = carve((size_t)24 * 4096 * 64);
  bf16* kb = carve((size_t)24 * 4096 * 64);
  bf16* vb = carve((size_t)24 * 4096 * 64);  // reused as yb
  bf16* vtb = xb;  // xb dead after QKV gemm
  bf16* yb = vb;   // vb dead after V transpose

  prep_kernel<<<5376, 256, 0, stream>>>(x, xb, w_attn, wt_attn, w_proj,
                                        wt_proj);
  gemm_kernel<1, 18><<<1152, 256, 0, stream>>>(xb, wt_attn, b_attn, 2304,
                                               nullptr, qb, kb, vb);
  transpose_bf16_kernel<<<dim3(64 / 32, 4096 / 32, 24), 256, 0, stream>>>(
      vb, vtb, 4096, 64);
  attn_kernel<<<dim3(768), 512, 0, stream>>>(qb, kb, vtb, yb);
  gemm_kernel<0, 6><<<384, 256, 0, stream>>>(yb, wt_proj, b_proj, 768, out,
                                             nullptr, nullptr, nullptr);
}